// Round 3
// baseline (2636.866 us; speedup 1.0000x reference)
//
#include <hip/hip_runtime.h>

#define NB 16  // batch / NSEQ

// ---------------------------------------------------------------- utilities
__device__ __forceinline__ float hat_cdf(float t) {
    t = fminf(fmaxf(t, -1.f), 1.f);
    if (t < 0.f) { float u = t + 1.f; return 0.5f * u * u; }
    float u = 1.f - t; return 1.f - 0.5f * u * u;
}

// scal layout (doubles): [0..7] = S sums (layer*2 + {t,s}), [8] = loss accum
__global__ void init_kernel(double* scal) {
    int i = threadIdx.x;
    if (i < 16) scal[i] = 0.0;
}

__global__ void fin_kernel(const double* scal, float* out) {
    out[0] = (float)scal[8];
}

// ---------------------------------------------------------------- PrRoI pool
// patch[r,c,p,q] = (1/area) * sum_{h,w} wy[r,p,h]*wx[r,q,w]*feat[r,c,h,w]
// Exact hat-kernel bin integrals; window [ceil(e0-1), floor(e1+1)] covers the
// support of cdf(e1-g)-cdf(e0-g) (zero-weight endpoints harmless).
__global__ void pool_kernel(const float* __restrict__ feat, const float* __restrict__ bb,
                            float* __restrict__ patch, int C, int H, int W,
                            int psz, float scale) {
    int rc = blockIdx.x;
    int r = rc / C, c = rc - r * C;
    int PP = psz * psz;
    int pq = threadIdx.x;
    if (pq >= PP) return;
    int p = pq / psz, q = pq - p * psz;

    float bx = bb[r * 4 + 0], by = bb[r * 4 + 1];
    float bwid = bb[r * 4 + 2], bhgt = bb[r * 4 + 3];
    float x1 = bx * scale, y1 = by * scale;
    float x2 = (bx + bwid) * scale, y2 = (by + bhgt) * scale;
    float bw = (x2 - x1) / (float)psz, bh = (y2 - y1) / (float)psz;

    float ey0 = y1 + p * bh, ey1 = ey0 + bh;
    float ex0 = x1 + q * bw, ex1 = ex0 + bw;
    int ylo = max(0, (int)ceilf(ey0 - 1.f));
    int yhi = min(H - 1, (int)floorf(ey1 + 1.f));
    int xlo = max(0, (int)ceilf(ex0 - 1.f));
    int xhi = min(W - 1, (int)floorf(ex1 + 1.f));

    const float* f = feat + ((size_t)r * C + c) * H * W;
    float acc = 0.f;
    for (int h = ylo; h <= yhi; ++h) {
        float wy = hat_cdf(ey1 - (float)h) - hat_cdf(ey0 - (float)h);
        float ra = 0.f;
        for (int w = xlo; w <= xhi; ++w) {
            float wx = hat_cdf(ex1 - (float)w) - hat_cdf(ex0 - (float)w);
            ra = fmaf(wx, f[h * W + w], ra);
        }
        acc = fmaf(wy, ra, acc);
    }
    float area = fmaxf(bw, 0.f) * fmaxf(bh, 0.f);
    float inv = area > 0.f ? 1.f / fmaxf(area, 1e-12f) : 0.f;
    patch[((size_t)r * C + c) * PP + pq] = acc * inv;
}

// tq[r,p,q] = sum_c |patch[r,c,p,q]|
__global__ void tq_kernel(const float* __restrict__ patch, float* __restrict__ tq,
                          int C, int PP) {
    int idx = blockIdx.x * blockDim.x + threadIdx.x;
    if (idx >= NB * PP) return;
    int r = idx / PP, pq = idx - r * PP;
    const float* p = patch + (size_t)r * C * PP + pq;
    float s = 0.f;
    for (int c = 0; c < C; ++c) s += fabsf(p[(size_t)c * PP]);
    tq[idx] = s;
}

// sa[b,y,x] = sum_c |in[b,c,y,x]|
__global__ void sumabs_kernel(const float* __restrict__ in, float* __restrict__ sa,
                              int C, int HW) {
    int idx = blockIdx.x * blockDim.x + threadIdx.x;
    if (idx >= NB * HW) return;
    int b = idx / HW, yx = idx - b * HW;
    const float* p = in + (size_t)b * C * HW + yx;
    float s = 0.f;
    for (int c = 0; c < C; ++c) s += fabsf(p[(size_t)c * HW]);
    sa[idx] = s;
}

// ---------------------------------------------------------------- correlation
// corr[b,y,x] = sum_{c,i,j} test[b,c,y+i-pad,x+j-pad] * patch[b,c,i,j]
// 64x64 output tile per block; 256 threads = 8x32; 2 rows x 8 cols per thread.
// Patch values are wave-uniform -> scalar loads (s_load), zero vector traffic.
// Channels split into nCh chunks, each writing a private partial plane
// corr_part[chunk][b][H][W] (summed in loss2_kernel). Per-block partial sum of
// corr is double-atomicAdd'ed into S_slot.
template <int PSZ>
__global__ __launch_bounds__(256)
void corr_kernel(const float* __restrict__ test, const float* __restrict__ patch,
                 float* __restrict__ corr_part, double* __restrict__ S_slot,
                 int C, int H, int W, int cc, int tilesX, int nCh) {
    constexpr int PAD = (PSZ - 1) / 2;
    constexpr int IH = 63 + PSZ;
    constexpr int IW = (IH + 3) & ~3;       // rows 16B-aligned for float4
    constexpr int NQ = (PSZ + 10) / 4;      // quads covering cols [cx0, cx0+PSZ+7)
    __shared__ __align__(16) float s_in[IH * IW];
    __shared__ float s_red[256];

    int bid = blockIdx.x;
    int chunk = bid % nCh; bid /= nCh;
    int tX = bid % tilesX; bid /= tilesX;
    int tY = bid % tilesX; bid /= tilesX;   // square tiling
    int b = bid;
    int tx0 = tX * 64, ty0 = tY * 64;

    int tid = threadIdx.x;
    int thrX = tid & 7;        // 8 threads across  -> 8*8 = 64 cols
    int thrY = tid >> 3;       // 32 threads down   -> 32*2 = 64 rows
    int cx0 = thrX * 8;
    int ry0 = thrY * 2;

    float acc[2][8];
#pragma unroll
    for (int k = 0; k < 2; ++k)
#pragma unroll
        for (int d = 0; d < 8; ++d) acc[k][d] = 0.f;

    int c_beg = chunk * cc;
    for (int c = c_beg; c < c_beg + cc; ++c) {
        // stage input tile (zero-padded)
        const float* gsrc = test + ((size_t)(b * C + c)) * H * W;
        for (int li = tid; li < IH * IW; li += 256) {
            int iy = li / IW, ix = li - iy * IW;
            int gy = ty0 - PAD + iy, gx = tx0 - PAD + ix;
            float v = 0.f;
            if ((unsigned)gy < (unsigned)H && (unsigned)gx < (unsigned)W)
                v = gsrc[gy * W + gx];
            s_in[li] = v;
        }
        __syncthreads();

        const float* prow_base = patch + ((size_t)(b * C + c)) * (PSZ * PSZ);
        for (int i = 0; i < PSZ; ++i) {
            const float* pr = prow_base + i * PSZ;  // wave-uniform -> s_load
            float w0[NQ * 4], w1[NQ * 4];
            const float4* r0 = reinterpret_cast<const float4*>(&s_in[(ry0 + i) * IW + cx0]);
            const float4* r1 = reinterpret_cast<const float4*>(&s_in[(ry0 + 1 + i) * IW + cx0]);
#pragma unroll
            for (int n = 0; n < NQ; ++n) {
                float4 a = r0[n];
                w0[4 * n] = a.x; w0[4 * n + 1] = a.y; w0[4 * n + 2] = a.z; w0[4 * n + 3] = a.w;
                float4 bq = r1[n];
                w1[4 * n] = bq.x; w1[4 * n + 1] = bq.y; w1[4 * n + 2] = bq.z; w1[4 * n + 3] = bq.w;
            }
#pragma unroll
            for (int j = 0; j < PSZ; ++j) {
                float pv = pr[j];
#pragma unroll
                for (int d = 0; d < 8; ++d) {
                    acc[0][d] = fmaf(w0[j + d], pv, acc[0][d]);
                    acc[1][d] = fmaf(w1[j + d], pv, acc[1][d]);
                }
            }
        }
        __syncthreads();
    }

    // store valid outputs + per-block partial sum
    float psum = 0.f;
    float* cp = corr_part + ((size_t)(chunk * NB + b)) * H * W;
#pragma unroll
    for (int k = 0; k < 2; ++k) {
        int oy = ty0 + ry0 + k;
        if (oy < H) {
#pragma unroll
            for (int d = 0; d < 8; ++d) {
                int ox = tx0 + cx0 + d;
                if (ox < W) { cp[oy * W + ox] = acc[k][d]; psum += acc[k][d]; }
            }
        }
    }
    s_red[tid] = psum;
    __syncthreads();
    for (int s = 128; s > 0; s >>= 1) {
        if (tid < s) s_red[tid] += s_red[tid + s];
        __syncthreads();
    }
    if (tid == 0) atomicAdd(S_slot, (double)s_red[0]);
}

// ---------------------------------------------------------------- losses
// loss += mean((a-b)^2)
__global__ void loss1_kernel(const float* __restrict__ a, const float* __restrict__ b,
                             int n, double inv_n, double* loss) {
    __shared__ double red[256];
    double sd = 0.0;
    for (int idx = blockIdx.x * blockDim.x + threadIdx.x; idx < n;
         idx += blockDim.x * gridDim.x) {
        float d = a[idx] - b[idx];
        sd += (double)d * (double)d;
    }
    red[threadIdx.x] = sd;
    __syncthreads();
    for (int s = 128; s > 0; s >>= 1) {
        if (threadIdx.x < s) red[threadIdx.x] += red[threadIdx.x + s];
        __syncthreads();
    }
    if (threadIdx.x == 0) atomicAdd(loss, red[0] * inv_n);
}

// loss += mean_{b,y,x} ( |corr_s|*sa_s/|S_s| - |corr_t|*sa_t/|S_t| )^2
// Uses qt = sum_c|tt*wt| = |corr_t|*sa_t/|S_t| (wt = corr_t/S_t is a scalar
// per spatial location; |tt*wt| factorizes).
__global__ void loss2_kernel(const float* __restrict__ cp_t, const float* __restrict__ cp_s,
                             const float* __restrict__ sa_t, const float* __restrict__ sa_s,
                             const double* __restrict__ S2, int nCh, int HW,
                             double* loss) {
    int n = NB * HW;
    float rt = 1.f / fabsf((float)S2[0]);
    float rs = 1.f / fabsf((float)S2[1]);
    __shared__ double red[256];
    double sd = 0.0;
    size_t plane = (size_t)NB * HW;
    for (int idx = blockIdx.x * blockDim.x + threadIdx.x; idx < n;
         idx += blockDim.x * gridDim.x) {
        float ct = 0.f, cs = 0.f;
        for (int ch = 0; ch < nCh; ++ch) {
            ct += cp_t[ch * plane + idx];
            cs += cp_s[ch * plane + idx];
        }
        float qt = fabsf(ct) * sa_t[idx] * rt;
        float qs = fabsf(cs) * sa_s[idx] * rs;
        float d = qs - qt;
        sd += (double)d * (double)d;
    }
    red[threadIdx.x] = sd;
    __syncthreads();
    for (int s = 128; s > 0; s >>= 1) {
        if (threadIdx.x < s) red[threadIdx.x] += red[threadIdx.x + s];
        __syncthreads();
    }
    if (threadIdx.x == 0) atomicAdd(loss, red[0] / (double)n);
}

// ---------------------------------------------------------------- host side
struct LayerCfg { int psz; float ds; int C; int H; int tilesX; int nCh; int cc; };

static const LayerCfg g_layers[4] = {
    {29, 0.5f,     64, 112, 2, 16, 4},   // conv1
    {15, 0.25f,    64,  56, 1, 64, 1},   // layer1
    { 9, 0.125f,  128,  28, 1, 64, 2},   // layer2
    { 5, 0.0625f, 256,  14, 1, 64, 4},   // layer3
};

static void launch_corr(int psz, dim3 grid, hipStream_t st,
                        const float* test, const float* patch, float* cp, double* Ss,
                        int C, int H, int W, int cc, int tilesX, int nCh) {
    switch (psz) {
        case 29: corr_kernel<29><<<grid, 256, 0, st>>>(test, patch, cp, Ss, C, H, W, cc, tilesX, nCh); break;
        case 15: corr_kernel<15><<<grid, 256, 0, st>>>(test, patch, cp, Ss, C, H, W, cc, tilesX, nCh); break;
        case  9: corr_kernel< 9><<<grid, 256, 0, st>>>(test, patch, cp, Ss, C, H, W, cc, tilesX, nCh); break;
        case  5: corr_kernel< 5><<<grid, 256, 0, st>>>(test, patch, cp, Ss, C, H, W, cc, tilesX, nCh); break;
    }
}

extern "C" void kernel_launch(void* const* d_in, const int* in_sizes, int n_in,
                              void* d_out, int out_size, void* d_ws, size_t ws_size,
                              hipStream_t stream) {
    (void)in_sizes; (void)n_in; (void)out_size; (void)ws_size;

    const float* ref_s[4]  = {(const float*)d_in[0],  (const float*)d_in[1],
                              (const float*)d_in[2],  (const float*)d_in[3]};
    const float* test_s[4] = {(const float*)d_in[4],  (const float*)d_in[5],
                              (const float*)d_in[6],  (const float*)d_in[7]};
    const float* ref_t[4]  = {(const float*)d_in[8],  (const float*)d_in[9],
                              (const float*)d_in[10], (const float*)d_in[11]};
    const float* test_t[4] = {(const float*)d_in[12], (const float*)d_in[13],
                              (const float*)d_in[14], (const float*)d_in[15]};
    const float* bb = (const float*)d_in[16];
    float* out = (float*)d_out;

    // workspace layout (floats; ~34.3 MB total)
    const size_t PATCH_MAX = (size_t)NB * 64 * 29 * 29;   //   861,184 f
    const size_t CP_MAX    = (size_t)16 * NB * 112 * 112; // 3,211,264 f (=64*16*56*56)
    const size_t SA_MAX    = (size_t)NB * 112 * 112;      //   200,704 f
    const size_t TQ_MAX    = (size_t)NB * 29 * 29;        //    13,456 f

    char* ws = (char*)d_ws;
    double* scal = (double*)ws;                  // 16 doubles
    float* fbase = (float*)(ws + 128);
    float* patch_t = fbase;
    float* patch_s = patch_t + PATCH_MAX;
    float* cp_t    = patch_s + PATCH_MAX;
    float* cp_s    = cp_t + CP_MAX;
    float* sa_t    = cp_s + CP_MAX;
    float* sa_s    = sa_t + SA_MAX;
    float* tq_t    = sa_s + SA_MAX;
    float* tq_s    = tq_t + TQ_MAX;

    init_kernel<<<1, 32, 0, stream>>>(scal);

    for (int l = 0; l < 4; ++l) {
        const LayerCfg& L = g_layers[l];
        int H = L.H, W = L.H, C = L.C, psz = L.psz;
        int PP = psz * psz, HW = H * W;

        // PrRoI pooling (patches from ref features)
        int pool_blk = ((PP + 63) / 64) * 64;
        pool_kernel<<<dim3(NB * C), pool_blk, 0, stream>>>(ref_t[l], bb, patch_t, C, H, W, psz, L.ds);
        pool_kernel<<<dim3(NB * C), pool_blk, 0, stream>>>(ref_s[l], bb, patch_s, C, H, W, psz, L.ds);

        // tq = sum_c |patch|
        int ntq = NB * PP;
        tq_kernel<<<dim3((ntq + 255) / 256), 256, 0, stream>>>(patch_t, tq_t, C, PP);
        tq_kernel<<<dim3((ntq + 255) / 256), 256, 0, stream>>>(patch_s, tq_s, C, PP);

        // correlation (chunked partial planes + global S sums)
        dim3 cgrid(NB * L.tilesX * L.tilesX * L.nCh);
        launch_corr(psz, cgrid, stream, test_t[l], patch_t, cp_t, scal + 2 * l + 0,
                    C, H, W, L.cc, L.tilesX, L.nCh);
        launch_corr(psz, cgrid, stream, test_s[l], patch_s, cp_s, scal + 2 * l + 1,
                    C, H, W, L.cc, L.tilesX, L.nCh);

        // channel abs-sums of test features
        int nsa = NB * HW;
        sumabs_kernel<<<dim3((nsa + 255) / 256), 256, 0, stream>>>(test_t[l], sa_t, C, HW);
        sumabs_kernel<<<dim3((nsa + 255) / 256), 256, 0, stream>>>(test_s[l], sa_s, C, HW);

        // losses
        loss1_kernel<<<dim3(16), 256, 0, stream>>>(tq_s, tq_t, ntq, 1.0 / (double)ntq, scal + 8);
        loss2_kernel<<<dim3(256), 256, 0, stream>>>(cp_t, cp_s, sa_t, sa_s, scal + 2 * l,
                                                    L.nCh, HW, scal + 8);
    }

    fin_kernel<<<1, 1, 0, stream>>>(scal, out);
}

// Round 5
// 1889.558 us; speedup vs baseline: 1.3955x; 1.3955x over previous
//
#include <hip/hip_runtime.h>

#define NB 16  // batch / NSEQ

// ---------------------------------------------------------------- utilities
__device__ __forceinline__ float hat_cdf(float t) {
    t = fminf(fmaxf(t, -1.f), 1.f);
    if (t < 0.f) { float u = t + 1.f; return 0.5f * u * u; }
    float u = 1.f - t; return 1.f - 0.5f * u * u;
}

// scal layout (doubles): [0..7] = S sums (layer*2 + {t,s}), [8] = loss accum
__global__ void init_kernel(double* scal) {
    int i = threadIdx.x;
    if (i < 16) scal[i] = 0.0;
}

__global__ void fin_kernel(const double* scal, float* out) {
    out[0] = (float)scal[8];
}

// ---------------------------------------------------------------- PrRoI pool
// patch[r,c,p,q] = (1/area) * sum_{h,w} wy[r,p,h]*wx[r,q,w]*feat[r,c,h,w]
__global__ void pool_kernel(const float* __restrict__ feat, const float* __restrict__ bb,
                            float* __restrict__ patch, int C, int H, int W,
                            int psz, float scale) {
    int rc = blockIdx.x;
    int r = rc / C, c = rc - r * C;
    int PP = psz * psz;
    int pq = threadIdx.x;
    if (pq >= PP) return;
    int p = pq / psz, q = pq - p * psz;

    float bx = bb[r * 4 + 0], by = bb[r * 4 + 1];
    float bwid = bb[r * 4 + 2], bhgt = bb[r * 4 + 3];
    float x1 = bx * scale, y1 = by * scale;
    float x2 = (bx + bwid) * scale, y2 = (by + bhgt) * scale;
    float bw = (x2 - x1) / (float)psz, bh = (y2 - y1) / (float)psz;

    float ey0 = y1 + p * bh, ey1 = ey0 + bh;
    float ex0 = x1 + q * bw, ex1 = ex0 + bw;
    int ylo = max(0, (int)ceilf(ey0 - 1.f));
    int yhi = min(H - 1, (int)floorf(ey1 + 1.f));
    int xlo = max(0, (int)ceilf(ex0 - 1.f));
    int xhi = min(W - 1, (int)floorf(ex1 + 1.f));

    const float* f = feat + ((size_t)r * C + c) * H * W;
    float acc = 0.f;
    for (int h = ylo; h <= yhi; ++h) {
        float wy = hat_cdf(ey1 - (float)h) - hat_cdf(ey0 - (float)h);
        float ra = 0.f;
        for (int w = xlo; w <= xhi; ++w) {
            float wx = hat_cdf(ex1 - (float)w) - hat_cdf(ex0 - (float)w);
            ra = fmaf(wx, f[h * W + w], ra);
        }
        acc = fmaf(wy, ra, acc);
    }
    float area = fmaxf(bw, 0.f) * fmaxf(bh, 0.f);
    float inv = area > 0.f ? 1.f / fmaxf(area, 1e-12f) : 0.f;
    patch[((size_t)r * C + c) * PP + pq] = acc * inv;
}

// tq[r,p,q] = sum_c |patch[r,c,p,q]|
__global__ void tq_kernel(const float* __restrict__ patch, float* __restrict__ tq,
                          int C, int PP) {
    int idx = blockIdx.x * blockDim.x + threadIdx.x;
    if (idx >= NB * PP) return;
    int r = idx / PP, pq = idx - r * PP;
    const float* p = patch + (size_t)r * C * PP + pq;
    float s = 0.f;
    for (int c = 0; c < C; ++c) s += fabsf(p[(size_t)c * PP]);
    tq[idx] = s;
}

// sa[b,y,x] = sum_c |in[b,c,y,x]|
__global__ void sumabs_kernel(const float* __restrict__ in, float* __restrict__ sa,
                              int C, int HW) {
    int idx = blockIdx.x * blockDim.x + threadIdx.x;
    if (idx >= NB * HW) return;
    int b = idx / HW, yx = idx - b * HW;
    const float* p = in + (size_t)b * C * HW + yx;
    float s = 0.f;
    for (int c = 0; c < C; ++c) s += fabsf(p[(size_t)c * HW]);
    sa[idx] = s;
}

// ---------------------------------------------------------------- correlation
// corr[b,y,x] = sum_{c,i,j} test[b,c,y+i-pad,x+j-pad] * patch[b,c,i,j]
// 64x64 output tile per block; 256 threads = 8x32; 2 rows x 8 cols per thread.
//
// LDS XOR swizzle (R3 fix): natural layout gave bank-group
// g=(6*thrY+2*thrX+c) mod 8 -> even-only -> 16 of 32 banks, 16 acc/bank
// (2x the b128 minimum): SQ_LDS_BANK_CONFLICT=2.83e8 ~= 65% of CU cycles.
// XOR quad-LSB on rows with (row>>1)&1: odd-thrY lanes flip to odd bank
// groups -> 8 acc/bank, conflict-free. Bijective (quad pairs straddling a
// row boundary always land in same-sw row pairs (2m,2m+1); quad counts
// even); writer/reader use the same logical-row sw -> values identical,
// FMA order identical -> absmax stays 0.
template <int PSZ>
__global__ __launch_bounds__(256)
void corr_kernel(const float* __restrict__ test, const float* __restrict__ patch,
                 float* __restrict__ corr_part, double* __restrict__ S_slot,
                 int C, int H, int W, int cc, int tilesX, int nCh) {
    constexpr int PAD = (PSZ - 1) / 2;
    constexpr int IH = 63 + PSZ;
    constexpr int IW = (IH + 3) & ~3;       // rows 16B-aligned for float4
    constexpr int NQ = (PSZ + 10) / 4;      // quads covering cols [cx0, cx0+PSZ+7)
    __shared__ __align__(16) float s_in[IH * IW];
    __shared__ float s_red[256];

    int bid = blockIdx.x;
    int chunk = bid % nCh; bid /= nCh;
    int tX = bid % tilesX; bid /= tilesX;
    int tY = bid % tilesX; bid /= tilesX;   // square tiling
    int b = bid;
    int tx0 = tX * 64, ty0 = tY * 64;

    int tid = threadIdx.x;
    int thrX = tid & 7;        // 8 threads across  -> 8*8 = 64 cols
    int thrY = tid >> 3;       // 32 threads down   -> 32*2 = 64 rows
    int cx0 = thrX * 8;
    int ry0 = thrY * 2;

    float acc[2][8];
#pragma unroll
    for (int k = 0; k < 2; ++k)
#pragma unroll
        for (int d = 0; d < 8; ++d) acc[k][d] = 0.f;

    int c_beg = chunk * cc;
    for (int c = c_beg; c < c_beg + cc; ++c) {
        // stage input tile (zero-padded), swizzled write
        const float* gsrc = test + ((size_t)(b * C + c)) * H * W;
        for (int li = tid; li < IH * IW; li += 256) {
            int iy = li / IW, ix = li - iy * IW;
            int gy = ty0 - PAD + iy, gx = tx0 - PAD + ix;
            float v = 0.f;
            if ((unsigned)gy < (unsigned)H && (unsigned)gx < (unsigned)W)
                v = gsrc[gy * W + gx];
            s_in[li ^ (((iy >> 1) & 1) << 2)] = v;
        }
        __syncthreads();

        const float* prow_base = patch + ((size_t)(b * C + c)) * (PSZ * PSZ);
        for (int i = 0; i < PSZ; ++i) {
            const float* pr = prow_base + i * PSZ;  // wave-uniform -> s_load
            int row0 = ry0 + i;
            int row1 = row0 + 1;
            int base0 = row0 * IW + cx0;
            int base1 = row1 * IW + cx0;
            int sw0 = ((row0 >> 1) & 1) << 2;
            int sw1 = ((row1 >> 1) & 1) << 2;
            float w0[NQ * 4], w1[NQ * 4];
#pragma unroll
            for (int n = 0; n < NQ; ++n) {
                float4 a = *reinterpret_cast<const float4*>(&s_in[(base0 + 4 * n) ^ sw0]);
                w0[4 * n] = a.x; w0[4 * n + 1] = a.y; w0[4 * n + 2] = a.z; w0[4 * n + 3] = a.w;
                float4 bq = *reinterpret_cast<const float4*>(&s_in[(base1 + 4 * n) ^ sw1]);
                w1[4 * n] = bq.x; w1[4 * n + 1] = bq.y; w1[4 * n + 2] = bq.z; w1[4 * n + 3] = bq.w;
            }
#pragma unroll
            for (int j = 0; j < PSZ; ++j) {
                float pv = pr[j];
#pragma unroll
                for (int d = 0; d < 8; ++d) {
                    acc[0][d] = fmaf(w0[j + d], pv, acc[0][d]);
                    acc[1][d] = fmaf(w1[j + d], pv, acc[1][d]);
                }
            }
        }
        __syncthreads();
    }

    // store valid outputs + per-block partial sum
    float psum = 0.f;
    float* cp = corr_part + ((size_t)(chunk * NB + b)) * H * W;
#pragma unroll
    for (int k = 0; k < 2; ++k) {
        int oy = ty0 + ry0 + k;
        if (oy < H) {
#pragma unroll
            for (int d = 0; d < 8; ++d) {
                int ox = tx0 + cx0 + d;
                if (ox < W) { cp[oy * W + ox] = acc[k][d]; psum += acc[k][d]; }
            }
        }
    }
    s_red[tid] = psum;
    __syncthreads();
    for (int s = 128; s > 0; s >>= 1) {
        if (tid < s) s_red[tid] += s_red[tid + s];
        __syncthreads();
    }
    if (tid == 0) atomicAdd(S_slot, (double)s_red[0]);
}

// ---------------------------------------------------------------- losses
// loss += mean((a-b)^2)
__global__ void loss1_kernel(const float* __restrict__ a, const float* __restrict__ b,
                             int n, double inv_n, double* loss) {
    __shared__ double red[256];
    double sd = 0.0;
    for (int idx = blockIdx.x * blockDim.x + threadIdx.x; idx < n;
         idx += blockDim.x * gridDim.x) {
        float d = a[idx] - b[idx];
        sd += (double)d * (double)d;
    }
    red[threadIdx.x] = sd;
    __syncthreads();
    for (int s = 128; s > 0; s >>= 1) {
        if (threadIdx.x < s) red[threadIdx.x] += red[threadIdx.x + s];
        __syncthreads();
    }
    if (threadIdx.x == 0) atomicAdd(loss, red[0] * inv_n);
}

// loss += mean_{b,y,x} ( |corr_s|*sa_s/|S_s| - |corr_t|*sa_t/|S_t| )^2
__global__ void loss2_kernel(const float* __restrict__ cp_t, const float* __restrict__ cp_s,
                             const float* __restrict__ sa_t, const float* __restrict__ sa_s,
                             const double* __restrict__ S2, int nCh, int HW,
                             double* loss) {
    int n = NB * HW;
    float rt = 1.f / fabsf((float)S2[0]);
    float rs = 1.f / fabsf((float)S2[1]);
    __shared__ double red[256];
    double sd = 0.0;
    size_t plane = (size_t)NB * HW;
    for (int idx = blockIdx.x * blockDim.x + threadIdx.x; idx < n;
         idx += blockDim.x * gridDim.x) {
        float ct = 0.f, cs = 0.f;
        for (int ch = 0; ch < nCh; ++ch) {
            ct += cp_t[ch * plane + idx];
            cs += cp_s[ch * plane + idx];
        }
        float qt = fabsf(ct) * sa_t[idx] * rt;
        float qs = fabsf(cs) * sa_s[idx] * rs;
        float d = qs - qt;
        sd += (double)d * (double)d;
    }
    red[threadIdx.x] = sd;
    __syncthreads();
    for (int s = 128; s > 0; s >>= 1) {
        if (threadIdx.x < s) red[threadIdx.x] += red[threadIdx.x + s];
        __syncthreads();
    }
    if (threadIdx.x == 0) atomicAdd(loss, red[0] / (double)n);
}

// ---------------------------------------------------------------- host side
struct LayerCfg { int psz; float ds; int C; int H; int tilesX; int nCh; int cc; };

static const LayerCfg g_layers[4] = {
    {29, 0.5f,     64, 112, 2, 16, 4},   // conv1
    {15, 0.25f,    64,  56, 1, 64, 1},   // layer1
    { 9, 0.125f,  128,  28, 1, 64, 2},   // layer2
    { 5, 0.0625f, 256,  14, 1, 64, 4},   // layer3
};

static void launch_corr(int psz, dim3 grid, hipStream_t st,
                        const float* test, const float* patch, float* cp, double* Ss,
                        int C, int H, int W, int cc, int tilesX, int nCh) {
    switch (psz) {
        case 29: corr_kernel<29><<<grid, 256, 0, st>>>(test, patch, cp, Ss, C, H, W, cc, tilesX, nCh); break;
        case 15: corr_kernel<15><<<grid, 256, 0, st>>>(test, patch, cp, Ss, C, H, W, cc, tilesX, nCh); break;
        case  9: corr_kernel< 9><<<grid, 256, 0, st>>>(test, patch, cp, Ss, C, H, W, cc, tilesX, nCh); break;
        case  5: corr_kernel< 5><<<grid, 256, 0, st>>>(test, patch, cp, Ss, C, H, W, cc, tilesX, nCh); break;
    }
}

extern "C" void kernel_launch(void* const* d_in, const int* in_sizes, int n_in,
                              void* d_out, int out_size, void* d_ws, size_t ws_size,
                              hipStream_t stream) {
    (void)in_sizes; (void)n_in; (void)out_size; (void)ws_size;

    const float* ref_s[4]  = {(const float*)d_in[0],  (const float*)d_in[1],
                              (const float*)d_in[2],  (const float*)d_in[3]};
    const float* test_s[4] = {(const float*)d_in[4],  (const float*)d_in[5],
                              (const float*)d_in[6],  (const float*)d_in[7]};
    const float* ref_t[4]  = {(const float*)d_in[8],  (const float*)d_in[9],
                              (const float*)d_in[10], (const float*)d_in[11]};
    const float* test_t[4] = {(const float*)d_in[12], (const float*)d_in[13],
                              (const float*)d_in[14], (const float*)d_in[15]};
    const float* bb = (const float*)d_in[16];
    float* out = (float*)d_out;

    // workspace layout (floats; ~34.3 MB total)
    const size_t PATCH_MAX = (size_t)NB * 64 * 29 * 29;   //   861,184 f
    const size_t CP_MAX    = (size_t)16 * NB * 112 * 112; // 3,211,264 f (=64*16*56*56)
    const size_t SA_MAX    = (size_t)NB * 112 * 112;      //   200,704 f
    const size_t TQ_MAX    = (size_t)NB * 29 * 29;        //    13,456 f

    char* ws = (char*)d_ws;
    double* scal = (double*)ws;                  // 16 doubles
    float* fbase = (float*)(ws + 128);
    float* patch_t = fbase;
    float* patch_s = patch_t + PATCH_MAX;
    float* cp_t    = patch_s + PATCH_MAX;
    float* cp_s    = cp_t + CP_MAX;
    float* sa_t    = cp_s + CP_MAX;
    float* sa_s    = sa_t + SA_MAX;
    float* tq_t    = sa_s + SA_MAX;
    float* tq_s    = tq_t + TQ_MAX;

    init_kernel<<<1, 32, 0, stream>>>(scal);

    for (int l = 0; l < 4; ++l) {
        const LayerCfg& L = g_layers[l];
        int H = L.H, W = L.H, C = L.C, psz = L.psz;
        int PP = psz * psz, HW = H * W;

        // PrRoI pooling (patches from ref features)
        int pool_blk = ((PP + 63) / 64) * 64;
        pool_kernel<<<dim3(NB * C), pool_blk, 0, stream>>>(ref_t[l], bb, patch_t, C, H, W, psz, L.ds);
        pool_kernel<<<dim3(NB * C), pool_blk, 0, stream>>>(ref_s[l], bb, patch_s, C, H, W, psz, L.ds);

        // tq = sum_c |patch|
        int ntq = NB * PP;
        tq_kernel<<<dim3((ntq + 255) / 256), 256, 0, stream>>>(patch_t, tq_t, C, PP);
        tq_kernel<<<dim3((ntq + 255) / 256), 256, 0, stream>>>(patch_s, tq_s, C, PP);

        // correlation (chunked partial planes + global S sums)
        dim3 cgrid(NB * L.tilesX * L.tilesX * L.nCh);
        launch_corr(psz, cgrid, stream, test_t[l], patch_t, cp_t, scal + 2 * l + 0,
                    C, H, W, L.cc, L.tilesX, L.nCh);
        launch_corr(psz, cgrid, stream, test_s[l], patch_s, cp_s, scal + 2 * l + 1,
                    C, H, W, L.cc, L.tilesX, L.nCh);

        // channel abs-sums of test features
        int nsa = NB * HW;
        sumabs_kernel<<<dim3((nsa + 255) / 256), 256, 0, stream>>>(test_t[l], sa_t, C, HW);
        sumabs_kernel<<<dim3((nsa + 255) / 256), 256, 0, stream>>>(test_s[l], sa_s, C, HW);

        // losses
        loss1_kernel<<<dim3(16), 256, 0, stream>>>(tq_s, tq_t, ntq, 1.0 / (double)ntq, scal + 8);
        loss2_kernel<<<dim3(256), 256, 0, stream>>>(cp_t, cp_s, sa_t, sa_s, scal + 2 * l,
                                                    L.nCh, HW, scal + 8);
    }

    fin_kernel<<<1, 1, 0, stream>>>(scal, out);
}

// Round 6
// 1886.410 us; speedup vs baseline: 1.3978x; 1.0017x over previous
//
#include <hip/hip_runtime.h>

#define NB 16  // batch / NSEQ

// ---------------------------------------------------------------- utilities
__device__ __forceinline__ float hat_cdf(float t) {
    t = fminf(fmaxf(t, -1.f), 1.f);
    if (t < 0.f) { float u = t + 1.f; return 0.5f * u * u; }
    float u = 1.f - t; return 1.f - 0.5f * u * u;
}

// compile-time float4 component / slot select (folds to a plain register read
// under full unroll; no v_mov)
__device__ __forceinline__ float q4c(const float4& q, int c) {
    return c == 0 ? q.x : c == 1 ? q.y : c == 2 ? q.z : q.w;
}
__device__ __forceinline__ const float4& sel3(const float4& x, const float4& y,
                                              const float4& z, int s) {
    return s == 0 ? x : s == 1 ? y : z;
}

// scal layout (doubles): [0..7] = S sums (layer*2 + {t,s}), [8] = loss accum
__global__ void init_kernel(double* scal) {
    int i = threadIdx.x;
    if (i < 16) scal[i] = 0.0;
}

__global__ void fin_kernel(const double* scal, float* out) {
    out[0] = (float)scal[8];
}

// sum 2*nblk per-block partials -> scal2[0], scal2[1] (deterministic tree;
// replaces the 1024-way double-CAS atomic storm inside corr_kernel)
__global__ void reduce_S_kernel(const double* __restrict__ spart,
                                double* __restrict__ scal2, int nblk) {
    __shared__ double red[256];
    int tid = threadIdx.x;
    for (int which = 0; which < 2; ++which) {
        double s = 0.0;
        for (int i = tid; i < nblk; i += 256) s += spart[which * nblk + i];
        red[tid] = s;
        __syncthreads();
        for (int k = 128; k > 0; k >>= 1) {
            if (tid < k) red[tid] += red[tid + k];
            __syncthreads();
        }
        if (tid == 0) scal2[which] = red[0];
        __syncthreads();
    }
}

// ---------------------------------------------------------------- PrRoI pool
__global__ void pool_kernel(const float* __restrict__ feat, const float* __restrict__ bb,
                            float* __restrict__ patch, int C, int H, int W,
                            int psz, float scale) {
    int rc = blockIdx.x;
    int r = rc / C, c = rc - r * C;
    int PP = psz * psz;
    int pq = threadIdx.x;
    if (pq >= PP) return;
    int p = pq / psz, q = pq - p * psz;

    float bx = bb[r * 4 + 0], by = bb[r * 4 + 1];
    float bwid = bb[r * 4 + 2], bhgt = bb[r * 4 + 3];
    float x1 = bx * scale, y1 = by * scale;
    float x2 = (bx + bwid) * scale, y2 = (by + bhgt) * scale;
    float bw = (x2 - x1) / (float)psz, bh = (y2 - y1) / (float)psz;

    float ey0 = y1 + p * bh, ey1 = ey0 + bh;
    float ex0 = x1 + q * bw, ex1 = ex0 + bw;
    int ylo = max(0, (int)ceilf(ey0 - 1.f));
    int yhi = min(H - 1, (int)floorf(ey1 + 1.f));
    int xlo = max(0, (int)ceilf(ex0 - 1.f));
    int xhi = min(W - 1, (int)floorf(ex1 + 1.f));

    const float* f = feat + ((size_t)r * C + c) * H * W;
    float acc = 0.f;
    for (int h = ylo; h <= yhi; ++h) {
        float wy = hat_cdf(ey1 - (float)h) - hat_cdf(ey0 - (float)h);
        float ra = 0.f;
        for (int w = xlo; w <= xhi; ++w) {
            float wx = hat_cdf(ex1 - (float)w) - hat_cdf(ex0 - (float)w);
            ra = fmaf(wx, f[h * W + w], ra);
        }
        acc = fmaf(wy, ra, acc);
    }
    float area = fmaxf(bw, 0.f) * fmaxf(bh, 0.f);
    float inv = area > 0.f ? 1.f / fmaxf(area, 1e-12f) : 0.f;
    patch[((size_t)r * C + c) * PP + pq] = acc * inv;
}

// tq[r,p,q] = sum_c |patch[r,c,p,q]|
__global__ void tq_kernel(const float* __restrict__ patch, float* __restrict__ tq,
                          int C, int PP) {
    int idx = blockIdx.x * blockDim.x + threadIdx.x;
    if (idx >= NB * PP) return;
    int r = idx / PP, pq = idx - r * PP;
    const float* p = patch + (size_t)r * C * PP + pq;
    float s = 0.f;
    for (int c = 0; c < C; ++c) s += fabsf(p[(size_t)c * PP]);
    tq[idx] = s;
}

// sa[b,y,x] = sum_c |in[b,c,y,x]|
__global__ void sumabs_kernel(const float* __restrict__ in, float* __restrict__ sa,
                              int C, int HW) {
    int idx = blockIdx.x * blockDim.x + threadIdx.x;
    if (idx >= NB * HW) return;
    int b = idx / HW, yx = idx - b * HW;
    const float* p = in + (size_t)b * C * HW + yx;
    float s = 0.f;
    for (int c = 0; c < C; ++c) s += fabsf(p[(size_t)c * HW]);
    sa[idx] = s;
}

// ---------------------------------------------------------------- correlation
// corr[b,y,x] = sum_{c,i,j} test[b,c,y+i-pad,x+j-pad] * patch[b,c,i,j]
// 64x64 tile/block; 256 thr = 8x32; 2 rows x 8 cols per thread.
//
// R3 swizzle (measured: conflicts 2.83e8 -> 6.46e7, VALU 38->73%): XOR quad
// LSB on rows with (row>>1)&1; bijective, conflict-free b128 reads.
//
// R5 sliding window (measured VGPR=60 at R3: compiler couldn't keep w0[36]+
// w1[36] live -> LDS remat; FMA was only 42% of issue while VALUBusy 73%):
// keep 3 quads/row live (6 float4 + 16 acc ~ 55 regs), 4 taps per group,
// rotate+load-1. Same ds_read count, same FMA order (j ascending -> bit-exact).
// Wave-dead skip: waves with both output rows >= H skip compute entirely
// (barriers outside) -> saves 12.5% conv1 / ~50% l2 / ~75% l3 halo waste.
template <int PSZ>
__global__ __launch_bounds__(256, 4)
void corr_kernel(const float* __restrict__ test, const float* __restrict__ patch,
                 float* __restrict__ corr_part, double* __restrict__ Spart,
                 int C, int H, int W, int cc, int tilesX, int nCh) {
    constexpr int PAD = (PSZ - 1) / 2;
    constexpr int IH = 63 + PSZ;
    constexpr int IW = (IH + 3) & ~3;       // rows 16B-aligned
    constexpr int QW = IW / 4;              // quads per row
    constexpr int NQ = (PSZ + 10) / 4;      // quads per thread window
    constexpr int G  = PSZ / 4;             // full 4-tap groups (PSZ odd -> tail 1|3)
    __shared__ __align__(16) float4 s_in4[IH * QW];
    __shared__ float s_red[256];

    int bid = blockIdx.x;
    int chunk = bid % nCh; bid /= nCh;
    int tX = bid % tilesX; bid /= tilesX;
    int tY = bid % tilesX; bid /= tilesX;
    int b = bid;
    int tx0 = tX * 64, ty0 = tY * 64;

    int tid = threadIdx.x;
    int thrX = tid & 7;
    int thrY = tid >> 3;
    int cx0 = thrX * 8;
    int qx0 = thrX * 2;                     // quad col base
    int ry0 = thrY * 2;
    bool alive = (ty0 + ry0) < H;           // wave-uniform when whole wave dead

    float acc[2][8];
#pragma unroll
    for (int k = 0; k < 2; ++k)
#pragma unroll
        for (int d = 0; d < 8; ++d) acc[k][d] = 0.f;

    int c_beg = chunk * cc;
    for (int c = c_beg; c < c_beg + cc; ++c) {
        // stage input tile (zero-padded), swizzled write (same as R3)
        const float* gsrc = test + ((size_t)(b * C + c)) * H * W;
        float* sview = (float*)s_in4;
        for (int li = tid; li < IH * IW; li += 256) {
            int iy = li / IW, ix = li - iy * IW;
            int gy = ty0 - PAD + iy, gx = tx0 - PAD + ix;
            float v = 0.f;
            if ((unsigned)gy < (unsigned)H && (unsigned)gx < (unsigned)W)
                v = gsrc[gy * W + gx];
            sview[li ^ (((iy >> 1) & 1) << 2)] = v;
        }
        __syncthreads();

        if (alive) {
            const float* prow_base = patch + ((size_t)(b * C + c)) * (PSZ * PSZ);
            for (int i = 0; i < PSZ; ++i) {
                const float* pr = prow_base + i * PSZ;  // wave-uniform -> s_load
                int row0 = ry0 + i, row1 = row0 + 1;
                int s0 = (row0 >> 1) & 1, s1 = (row1 >> 1) & 1;
                int k0 = row0 * QW + qx0, k1 = row1 * QW + qx0;
                float4 a0 = s_in4[(k0 + 0) ^ s0], a1 = s_in4[(k0 + 1) ^ s0], a2 = s_in4[(k0 + 2) ^ s0];
                float4 b0 = s_in4[(k1 + 0) ^ s1], b1 = s_in4[(k1 + 1) ^ s1], b2 = s_in4[(k1 + 2) ^ s1];
#pragma unroll
                for (int g = 0; g < G; ++g) {
#pragma unroll
                    for (int t = 0; t < 4; ++t) {
                        float pv = pr[4 * g + t];
#pragma unroll
                        for (int d = 0; d < 8; ++d) {
                            int o = t + d;  // 0..10 -> slot o>>2, comp o&3
                            acc[0][d] = fmaf(q4c(sel3(a0, a1, a2, o >> 2), o & 3), pv, acc[0][d]);
                            acc[1][d] = fmaf(q4c(sel3(b0, b1, b2, o >> 2), o & 3), pv, acc[1][d]);
                        }
                    }
                    a0 = a1; a1 = a2; b0 = b1; b1 = b2;
                    if (g + 3 < NQ) {
                        a2 = s_in4[(k0 + g + 3) ^ s0];
                        b2 = s_in4[(k1 + g + 3) ^ s1];
                    }
                }
                // tail taps j = 4G..PSZ-1; slots 0..2 hold quads G,G+1,G+2(-as-loaded)
#pragma unroll
                for (int t = 0; t < PSZ - 4 * G; ++t) {
                    float pv = pr[4 * G + t];
#pragma unroll
                    for (int d = 0; d < 8; ++d) {
                        int o = t + d;
                        acc[0][d] = fmaf(q4c(sel3(a0, a1, a2, o >> 2), o & 3), pv, acc[0][d]);
                        acc[1][d] = fmaf(q4c(sel3(b0, b1, b2, o >> 2), o & 3), pv, acc[1][d]);
                    }
                }
            }
        }
        __syncthreads();
    }

    // store valid outputs + per-block partial sum (no atomics: Spart slot)
    float psum = 0.f;
    float* cp = corr_part + ((size_t)(chunk * NB + b)) * H * W;
#pragma unroll
    for (int k = 0; k < 2; ++k) {
        int oy = ty0 + ry0 + k;
        if (oy < H) {
#pragma unroll
            for (int d = 0; d < 8; ++d) {
                int ox = tx0 + cx0 + d;
                if (ox < W) { cp[oy * W + ox] = acc[k][d]; psum += acc[k][d]; }
            }
        }
    }
    s_red[tid] = psum;
    __syncthreads();
    for (int s = 128; s > 0; s >>= 1) {
        if (tid < s) s_red[tid] += s_red[tid + s];
        __syncthreads();
    }
    if (tid == 0) Spart[blockIdx.x] = (double)s_red[0];
}

// ---------------------------------------------------------------- losses
__global__ void loss1_kernel(const float* __restrict__ a, const float* __restrict__ b,
                             int n, double inv_n, double* loss) {
    __shared__ double red[256];
    double sd = 0.0;
    for (int idx = blockIdx.x * blockDim.x + threadIdx.x; idx < n;
         idx += blockDim.x * gridDim.x) {
        float d = a[idx] - b[idx];
        sd += (double)d * (double)d;
    }
    red[threadIdx.x] = sd;
    __syncthreads();
    for (int s = 128; s > 0; s >>= 1) {
        if (threadIdx.x < s) red[threadIdx.x] += red[threadIdx.x + s];
        __syncthreads();
    }
    if (threadIdx.x == 0) atomicAdd(loss, red[0] * inv_n);
}

__global__ void loss2_kernel(const float* __restrict__ cp_t, const float* __restrict__ cp_s,
                             const float* __restrict__ sa_t, const float* __restrict__ sa_s,
                             const double* __restrict__ S2, int nCh, int HW,
                             double* loss) {
    int n = NB * HW;
    float rt = 1.f / fabsf((float)S2[0]);
    float rs = 1.f / fabsf((float)S2[1]);
    __shared__ double red[256];
    double sd = 0.0;
    size_t plane = (size_t)NB * HW;
    for (int idx = blockIdx.x * blockDim.x + threadIdx.x; idx < n;
         idx += blockDim.x * gridDim.x) {
        float ct = 0.f, cs = 0.f;
        for (int ch = 0; ch < nCh; ++ch) {
            ct += cp_t[ch * plane + idx];
            cs += cp_s[ch * plane + idx];
        }
        float qt = fabsf(ct) * sa_t[idx] * rt;
        float qs = fabsf(cs) * sa_s[idx] * rs;
        float d = qs - qt;
        sd += (double)d * (double)d;
    }
    red[threadIdx.x] = sd;
    __syncthreads();
    for (int s = 128; s > 0; s >>= 1) {
        if (threadIdx.x < s) red[threadIdx.x] += red[threadIdx.x + s];
        __syncthreads();
    }
    if (threadIdx.x == 0) atomicAdd(loss, red[0] / (double)n);
}

// ---------------------------------------------------------------- host side
struct LayerCfg { int psz; float ds; int C; int H; int tilesX; int nCh; int cc; };

static const LayerCfg g_layers[4] = {
    {29, 0.5f,     64, 112, 2, 16, 4},   // conv1
    {15, 0.25f,    64,  56, 1, 64, 1},   // layer1
    { 9, 0.125f,  128,  28, 1, 64, 2},   // layer2
    { 5, 0.0625f, 256,  14, 1, 64, 4},   // layer3
};

static void launch_corr(int psz, dim3 grid, hipStream_t st,
                        const float* test, const float* patch, float* cp, double* Sp,
                        int C, int H, int W, int cc, int tilesX, int nCh) {
    switch (psz) {
        case 29: corr_kernel<29><<<grid, 256, 0, st>>>(test, patch, cp, Sp, C, H, W, cc, tilesX, nCh); break;
        case 15: corr_kernel<15><<<grid, 256, 0, st>>>(test, patch, cp, Sp, C, H, W, cc, tilesX, nCh); break;
        case  9: corr_kernel< 9><<<grid, 256, 0, st>>>(test, patch, cp, Sp, C, H, W, cc, tilesX, nCh); break;
        case  5: corr_kernel< 5><<<grid, 256, 0, st>>>(test, patch, cp, Sp, C, H, W, cc, tilesX, nCh); break;
    }
}

extern "C" void kernel_launch(void* const* d_in, const int* in_sizes, int n_in,
                              void* d_out, int out_size, void* d_ws, size_t ws_size,
                              hipStream_t stream) {
    (void)in_sizes; (void)n_in; (void)out_size; (void)ws_size;

    const float* ref_s[4]  = {(const float*)d_in[0],  (const float*)d_in[1],
                              (const float*)d_in[2],  (const float*)d_in[3]};
    const float* test_s[4] = {(const float*)d_in[4],  (const float*)d_in[5],
                              (const float*)d_in[6],  (const float*)d_in[7]};
    const float* ref_t[4]  = {(const float*)d_in[8],  (const float*)d_in[9],
                              (const float*)d_in[10], (const float*)d_in[11]};
    const float* test_t[4] = {(const float*)d_in[12], (const float*)d_in[13],
                              (const float*)d_in[14], (const float*)d_in[15]};
    const float* bb = (const float*)d_in[16];
    float* out = (float*)d_out;

    const int NBLK = 1024;  // NB * tilesX^2 * nCh for every layer config

    // workspace layout
    const size_t PATCH_MAX = (size_t)NB * 64 * 29 * 29;   //   861,184 f
    const size_t CP_MAX    = (size_t)16 * NB * 112 * 112; // 3,211,264 f
    const size_t SA_MAX    = (size_t)NB * 112 * 112;      //   200,704 f
    const size_t TQ_MAX    = (size_t)NB * 29 * 29;        //    13,456 f

    char* ws = (char*)d_ws;
    double* scal  = (double*)ws;            // 16 doubles
    double* spart = scal + 16;              // 2*NBLK doubles (t at 0, s at NBLK)
    float* fbase = (float*)(ws + (16 + 2 * NBLK) * sizeof(double) + 128);
    float* patch_t = fbase;
    float* patch_s = patch_t + PATCH_MAX;
    float* cp_t    = patch_s + PATCH_MAX;
    float* cp_s    = cp_t + CP_MAX;
    float* sa_t    = cp_s + CP_MAX;
    float* sa_s    = sa_t + SA_MAX;
    float* tq_t    = sa_s + SA_MAX;
    float* tq_s    = tq_t + TQ_MAX;

    init_kernel<<<1, 32, 0, stream>>>(scal);

    for (int l = 0; l < 4; ++l) {
        const LayerCfg& L = g_layers[l];
        int H = L.H, W = L.H, C = L.C, psz = L.psz;
        int PP = psz * psz, HW = H * W;

        int pool_blk = ((PP + 63) / 64) * 64;
        pool_kernel<<<dim3(NB * C), pool_blk, 0, stream>>>(ref_t[l], bb, patch_t, C, H, W, psz, L.ds);
        pool_kernel<<<dim3(NB * C), pool_blk, 0, stream>>>(ref_s[l], bb, patch_s, C, H, W, psz, L.ds);

        int ntq = NB * PP;
        tq_kernel<<<dim3((ntq + 255) / 256), 256, 0, stream>>>(patch_t, tq_t, C, PP);
        tq_kernel<<<dim3((ntq + 255) / 256), 256, 0, stream>>>(patch_s, tq_s, C, PP);

        dim3 cgrid(NB * L.tilesX * L.tilesX * L.nCh);
        launch_corr(psz, cgrid, stream, test_t[l], patch_t, cp_t, spart,
                    C, H, W, L.cc, L.tilesX, L.nCh);
        launch_corr(psz, cgrid, stream, test_s[l], patch_s, cp_s, spart + NBLK,
                    C, H, W, L.cc, L.tilesX, L.nCh);
        reduce_S_kernel<<<1, 256, 0, stream>>>(spart, scal + 2 * l, NBLK);

        int nsa = NB * HW;
        sumabs_kernel<<<dim3((nsa + 255) / 256), 256, 0, stream>>>(test_t[l], sa_t, C, HW);
        sumabs_kernel<<<dim3((nsa + 255) / 256), 256, 0, stream>>>(test_s[l], sa_s, C, HW);

        loss1_kernel<<<dim3(16), 256, 0, stream>>>(tq_s, tq_t, ntq, 1.0 / (double)ntq, scal + 8);
        loss2_kernel<<<dim3(256), 256, 0, stream>>>(cp_t, cp_s, sa_t, sa_s, scal + 2 * l,
                                                    L.nCh, HW, scal + 8);
    }

    fin_kernel<<<1, 1, 0, stream>>>(scal, out);
}

// Round 7
// 1387.411 us; speedup vs baseline: 1.9006x; 1.3597x over previous
//
#include <hip/hip_runtime.h>

#define NB 16  // batch / NSEQ

// ---------------------------------------------------------------- utilities
__device__ __forceinline__ float hat_cdf(float t) {
    t = fminf(fmaxf(t, -1.f), 1.f);
    if (t < 0.f) { float u = t + 1.f; return 0.5f * u * u; }
    float u = 1.f - t; return 1.f - 0.5f * u * u;
}

// scal layout (doubles): [0..7] = S sums (layer*2 + {t,s}), [8] = loss accum
__global__ void init_kernel(double* scal) {
    int i = threadIdx.x;
    if (i < 16) scal[i] = 0.0;
}

__global__ void fin_kernel(const double* scal, float* out) {
    out[0] = (float)scal[8];
}

// sum 2*nblk per-block partials -> scal2[0], scal2[1] (deterministic tree)
__global__ void reduce_S_kernel(const double* __restrict__ spart,
                                double* __restrict__ scal2, int nblk) {
    __shared__ double red[256];
    int tid = threadIdx.x;
    for (int which = 0; which < 2; ++which) {
        double s = 0.0;
        for (int i = tid; i < nblk; i += 256) s += spart[which * nblk + i];
        red[tid] = s;
        __syncthreads();
        for (int k = 128; k > 0; k >>= 1) {
            if (tid < k) red[tid] += red[tid + k];
            __syncthreads();
        }
        if (tid == 0) scal2[which] = red[0];
        __syncthreads();
    }
}

// ---------------------------------------------------------------- PrRoI pool
// fused t+s: first gridDim/2 blocks pool ref_t->patch_t, rest ref_s->patch_s
__global__ void pool_kernel(const float* __restrict__ ref_t, const float* __restrict__ ref_s,
                            const float* __restrict__ bb,
                            float* __restrict__ patch_t, float* __restrict__ patch_s,
                            int C, int H, int W, int psz, float scale) {
    int rc = blockIdx.x;
    int n1 = gridDim.x >> 1;
    int which = rc >= n1;
    if (which) rc -= n1;
    const float* feat = which ? ref_s : ref_t;
    float* patch = which ? patch_s : patch_t;

    int r = rc / C, c = rc - r * C;
    int PP = psz * psz;
    int pq = threadIdx.x;
    if (pq >= PP) return;
    int p = pq / psz, q = pq - p * psz;

    float bx = bb[r * 4 + 0], by = bb[r * 4 + 1];
    float bwid = bb[r * 4 + 2], bhgt = bb[r * 4 + 3];
    float x1 = bx * scale, y1 = by * scale;
    float x2 = (bx + bwid) * scale, y2 = (by + bhgt) * scale;
    float bw = (x2 - x1) / (float)psz, bh = (y2 - y1) / (float)psz;

    float ey0 = y1 + p * bh, ey1 = ey0 + bh;
    float ex0 = x1 + q * bw, ex1 = ex0 + bw;
    int ylo = max(0, (int)ceilf(ey0 - 1.f));
    int yhi = min(H - 1, (int)floorf(ey1 + 1.f));
    int xlo = max(0, (int)ceilf(ex0 - 1.f));
    int xhi = min(W - 1, (int)floorf(ex1 + 1.f));

    const float* f = feat + ((size_t)r * C + c) * H * W;
    float acc = 0.f;
    for (int h = ylo; h <= yhi; ++h) {
        float wy = hat_cdf(ey1 - (float)h) - hat_cdf(ey0 - (float)h);
        float ra = 0.f;
        for (int w = xlo; w <= xhi; ++w) {
            float wx = hat_cdf(ex1 - (float)w) - hat_cdf(ex0 - (float)w);
            ra = fmaf(wx, f[h * W + w], ra);
        }
        acc = fmaf(wy, ra, acc);
    }
    float area = fmaxf(bw, 0.f) * fmaxf(bh, 0.f);
    float inv = area > 0.f ? 1.f / fmaxf(area, 1e-12f) : 0.f;
    patch[((size_t)r * C + c) * PP + pq] = acc * inv;
}

// tq[r,p,q] = sum_c |patch[r,c,p,q]|   (fused t+s)
__global__ void tq_kernel(const float* __restrict__ patch_t, const float* __restrict__ patch_s,
                          float* __restrict__ tq_t, float* __restrict__ tq_s,
                          int C, int PP) {
    int idx = blockIdx.x * blockDim.x + threadIdx.x;
    int n1 = NB * PP;
    if (idx >= 2 * n1) return;
    const float* patch = patch_t;
    float* tq = tq_t;
    if (idx >= n1) { idx -= n1; patch = patch_s; tq = tq_s; }
    int r = idx / PP, pq = idx - r * PP;
    const float* p = patch + (size_t)r * C * PP + pq;
    float s = 0.f;
    for (int c = 0; c < C; ++c) s += fabsf(p[(size_t)c * PP]);
    tq[idx] = s;
}

// sa[b,y,x] = sum_c |in[b,c,y,x]|   (fused t+s)
__global__ void sumabs_kernel(const float* __restrict__ in_t, const float* __restrict__ in_s,
                              float* __restrict__ sa_t, float* __restrict__ sa_s,
                              int C, int HW) {
    int idx = blockIdx.x * blockDim.x + threadIdx.x;
    int n1 = NB * HW;
    if (idx >= 2 * n1) return;
    const float* in = in_t;
    float* sa = sa_t;
    if (idx >= n1) { idx -= n1; in = in_s; sa = sa_s; }
    int b = idx / HW, yx = idx - b * HW;
    const float* p = in + (size_t)b * C * HW + yx;
    float s = 0.f;
    for (int c = 0; c < C; ++c) s += fabsf(p[(size_t)c * HW]);
    sa[idx] = s;
}

// ---------------------------------------------------------------- correlation
// corr[b,y,x] = sum_{c,i,j} test[b,c,y+i-pad,x+j-pad] * patch[b,c,i,j]
// R6 thread map: 64x64 tile, 256 thr = 4 cols-of-16 x 64 rows-of-1.
//  - window/output amplification 44/16 = 2.75x (was 36/8): 11 b128/row.
//  - QW forced ODD: bank-group of quad read = (QW*row + 4*thrX + g) mod 8;
//    odd QW * thrY (0..15) sweeps all 8 residues twice per thrX, 4*thrX adds
//    {0,4,0,4} -> exactly 8 lanes per group = b128 minimum. Conflict-free by
//    construction, NO swizzle (R3/R5 parity-XOR only half-fixed the old map:
//    residual 7e7 conflict-cycles = 26% of dispatch).
//  - sliding 5-quad (20-float) window + 16 acc ~= 55 live VGPR: no remat.
//  - per-output add order (c,i,j ascending) unchanged -> corr planes bit-exact.
// Fused t+s: blocks [0,nblk) do t, [nblk,2nblk) do s; Spart indexed by raw bid.
template <int PSZ>
__global__ __launch_bounds__(256, 3)
void corr_kernel(const float* __restrict__ test_t, const float* __restrict__ test_s,
                 const float* __restrict__ patch_t, const float* __restrict__ patch_s,
                 float* __restrict__ cp_t, float* __restrict__ cp_s,
                 double* __restrict__ Spart,
                 int C, int H, int W, int cc, int tilesX, int nCh, int nblk) {
    constexpr int PAD = (PSZ - 1) / 2;
    constexpr int IH = 63 + PSZ;
    constexpr int QW_RAW = (IH + 3) / 4;
    constexpr int QW = (QW_RAW % 2 == 0) ? QW_RAW + 1 : QW_RAW;   // odd!
    constexpr int IW = QW * 4;
    constexpr int Q = (PSZ + 14) / 4 + 1;   // window quads (cols 0..PSZ+14)
    constexpr int G = PSZ / 4;              // full 4-tap groups
    constexpr int S = Q - 5;                // shifting groups
    constexpr int TAIL = PSZ - 4 * G;
    static_assert(S <= G, "window schedule");
    __shared__ __align__(16) float4 s_in4[IH * QW];
    __shared__ float s_red[256];

    int sidx = blockIdx.x;                  // Spart slot
    int bid = sidx;
    int which = bid >= nblk;
    if (which) bid -= nblk;
    const float* test = which ? test_s : test_t;
    const float* patch = which ? patch_s : patch_t;
    float* corr_part = which ? cp_s : cp_t;

    int chunk = bid % nCh; bid /= nCh;
    int tX = bid % tilesX; bid /= tilesX;
    int tY = bid % tilesX; bid /= tilesX;
    int b = bid;
    int tx0 = tX * 64, ty0 = tY * 64;

    int tid = threadIdx.x;
    int thrX = tid & 3;                     // 4 x 16 output cols
    int thrY = tid >> 2;                    // 64 x 1 output row
    int cx0 = thrX * 16;
    int qx0 = thrX * 4;
    int row = thrY;
    bool alive = (ty0 + row) < H;

    float acc[16];
#pragma unroll
    for (int d = 0; d < 16; ++d) acc[d] = 0.f;

    float* sview = (float*)s_in4;
    int c_beg = chunk * cc;
    for (int c = c_beg; c < c_beg + cc; ++c) {
        // stage input tile (zero-padded); b32 writes: lanes contiguous -> free
        const float* gsrc = test + ((size_t)(b * C + c)) * H * W;
        for (int li = tid; li < IH * IW; li += 256) {
            int iy = li / IW, ix = li - iy * IW;
            int gy = ty0 - PAD + iy, gx = tx0 - PAD + ix;
            float v = 0.f;
            if ((unsigned)gy < (unsigned)H && (unsigned)gx < (unsigned)W)
                v = gsrc[gy * W + gx];
            sview[li] = v;
        }
        __syncthreads();

        if (alive) {
            const float* prow_base = patch + ((size_t)(b * C + c)) * (PSZ * PSZ);
            for (int i = 0; i < PSZ; ++i) {
                const float* pr = prow_base + i * PSZ;  // wave-uniform -> s_load
                int kbase = (row + i) * QW + qx0;
                float wf[20];
#pragma unroll
                for (int n = 0; n < 5; ++n) {
                    float4 qv = s_in4[kbase + n];
                    wf[4 * n + 0] = qv.x; wf[4 * n + 1] = qv.y;
                    wf[4 * n + 2] = qv.z; wf[4 * n + 3] = qv.w;
                }
#pragma unroll
                for (int g = 0; g < G; ++g) {
#pragma unroll
                    for (int t = 0; t < 4; ++t) {
                        float pv = pr[4 * g + t];
                        constexpr int dummy = 0; (void)dummy;
                        int off = (g < S) ? t : 4 * (g - S) + t;  // unroll-const
#pragma unroll
                        for (int d = 0; d < 16; ++d)
                            acc[d] = fmaf(wf[off + d], pv, acc[d]);
                    }
                    if (g < S) {
#pragma unroll
                        for (int k = 0; k < 16; ++k) wf[k] = wf[k + 4];
                        float4 qv = s_in4[kbase + 5 + g];
                        wf[16] = qv.x; wf[17] = qv.y; wf[18] = qv.z; wf[19] = qv.w;
                    }
                }
#pragma unroll
                for (int t = 0; t < TAIL; ++t) {
                    float pv = pr[4 * G + t];
                    int off = 4 * (G - S) + t;
#pragma unroll
                    for (int d = 0; d < 16; ++d)
                        acc[d] = fmaf(wf[off + d], pv, acc[d]);
                }
            }
        }
        __syncthreads();
    }

    // store outputs + per-block partial sum (no atomics)
    float psum = 0.f;
    if (alive) {
        int oy = ty0 + row;
        float* cp = corr_part + ((size_t)(chunk * NB + b)) * H * W + (size_t)oy * W;
#pragma unroll
        for (int s4 = 0; s4 < 4; ++s4) {
            int ox = tx0 + cx0 + 4 * s4;
            if (ox + 3 < W) {
                float4 v = make_float4(acc[4 * s4], acc[4 * s4 + 1],
                                       acc[4 * s4 + 2], acc[4 * s4 + 3]);
                *reinterpret_cast<float4*>(&cp[ox]) = v;
                psum += acc[4 * s4] + acc[4 * s4 + 1] + acc[4 * s4 + 2] + acc[4 * s4 + 3];
            } else {
#pragma unroll
                for (int e = 0; e < 4; ++e) {
                    if (ox + e < W) { cp[ox + e] = acc[4 * s4 + e]; psum += acc[4 * s4 + e]; }
                }
            }
        }
    }
    s_red[tid] = psum;
    __syncthreads();
    for (int s = 128; s > 0; s >>= 1) {
        if (tid < s) s_red[tid] += s_red[tid + s];
        __syncthreads();
    }
    if (tid == 0) Spart[sidx] = (double)s_red[0];
}

// ---------------------------------------------------------------- losses
__global__ void loss1_kernel(const float* __restrict__ a, const float* __restrict__ b,
                             int n, double inv_n, double* loss) {
    __shared__ double red[256];
    double sd = 0.0;
    for (int idx = blockIdx.x * blockDim.x + threadIdx.x; idx < n;
         idx += blockDim.x * gridDim.x) {
        float d = a[idx] - b[idx];
        sd += (double)d * (double)d;
    }
    red[threadIdx.x] = sd;
    __syncthreads();
    for (int s = 128; s > 0; s >>= 1) {
        if (threadIdx.x < s) red[threadIdx.x] += red[threadIdx.x + s];
        __syncthreads();
    }
    if (threadIdx.x == 0) atomicAdd(loss, red[0] * inv_n);
}

__global__ void loss2_kernel(const float* __restrict__ cp_t, const float* __restrict__ cp_s,
                             const float* __restrict__ sa_t, const float* __restrict__ sa_s,
                             const double* __restrict__ S2, int nCh, int HW,
                             double* loss) {
    int n = NB * HW;
    float rt = 1.f / fabsf((float)S2[0]);
    float rs = 1.f / fabsf((float)S2[1]);
    __shared__ double red[256];
    double sd = 0.0;
    size_t plane = (size_t)NB * HW;
    for (int idx = blockIdx.x * blockDim.x + threadIdx.x; idx < n;
         idx += blockDim.x * gridDim.x) {
        float ct = 0.f, cs = 0.f;
        for (int ch = 0; ch < nCh; ++ch) {
            ct += cp_t[ch * plane + idx];
            cs += cp_s[ch * plane + idx];
        }
        float qt = fabsf(ct) * sa_t[idx] * rt;
        float qs = fabsf(cs) * sa_s[idx] * rs;
        float d = qs - qt;
        sd += (double)d * (double)d;
    }
    red[threadIdx.x] = sd;
    __syncthreads();
    for (int s = 128; s > 0; s >>= 1) {
        if (threadIdx.x < s) red[threadIdx.x] += red[threadIdx.x + s];
        __syncthreads();
    }
    if (threadIdx.x == 0) atomicAdd(loss, red[0] / (double)n);
}

// ---------------------------------------------------------------- host side
struct LayerCfg { int psz; float ds; int C; int H; int tilesX; int nCh; int cc; };

static const LayerCfg g_layers[4] = {
    {29, 0.5f,     64, 112, 2, 16, 4},   // conv1
    {15, 0.25f,    64,  56, 1, 64, 1},   // layer1
    { 9, 0.125f,  128,  28, 1, 64, 2},   // layer2
    { 5, 0.0625f, 256,  14, 1, 64, 4},   // layer3
};

static void launch_corr(int psz, dim3 grid, hipStream_t st,
                        const float* tt, const float* ts, const float* pt, const float* ps,
                        float* ct, float* cs, double* Sp,
                        int C, int H, int W, int cc, int tilesX, int nCh, int nblk) {
    switch (psz) {
        case 29: corr_kernel<29><<<grid, 256, 0, st>>>(tt, ts, pt, ps, ct, cs, Sp, C, H, W, cc, tilesX, nCh, nblk); break;
        case 15: corr_kernel<15><<<grid, 256, 0, st>>>(tt, ts, pt, ps, ct, cs, Sp, C, H, W, cc, tilesX, nCh, nblk); break;
        case  9: corr_kernel< 9><<<grid, 256, 0, st>>>(tt, ts, pt, ps, ct, cs, Sp, C, H, W, cc, tilesX, nCh, nblk); break;
        case  5: corr_kernel< 5><<<grid, 256, 0, st>>>(tt, ts, pt, ps, ct, cs, Sp, C, H, W, cc, tilesX, nCh, nblk); break;
    }
}

extern "C" void kernel_launch(void* const* d_in, const int* in_sizes, int n_in,
                              void* d_out, int out_size, void* d_ws, size_t ws_size,
                              hipStream_t stream) {
    (void)in_sizes; (void)n_in; (void)out_size; (void)ws_size;

    const float* ref_s[4]  = {(const float*)d_in[0],  (const float*)d_in[1],
                              (const float*)d_in[2],  (const float*)d_in[3]};
    const float* test_s[4] = {(const float*)d_in[4],  (const float*)d_in[5],
                              (const float*)d_in[6],  (const float*)d_in[7]};
    const float* ref_t[4]  = {(const float*)d_in[8],  (const float*)d_in[9],
                              (const float*)d_in[10], (const float*)d_in[11]};
    const float* test_t[4] = {(const float*)d_in[12], (const float*)d_in[13],
                              (const float*)d_in[14], (const float*)d_in[15]};
    const float* bb = (const float*)d_in[16];
    float* out = (float*)d_out;

    const int NBLK = 1024;  // NB * tilesX^2 * nCh for every layer config

    const size_t PATCH_MAX = (size_t)NB * 64 * 29 * 29;
    const size_t CP_MAX    = (size_t)16 * NB * 112 * 112;
    const size_t SA_MAX    = (size_t)NB * 112 * 112;
    const size_t TQ_MAX    = (size_t)NB * 29 * 29;

    char* ws = (char*)d_ws;
    double* scal  = (double*)ws;            // 16 doubles
    double* spart = scal + 16;              // 2*NBLK doubles
    float* fbase = (float*)(ws + (16 + 2 * NBLK) * sizeof(double) + 128);
    float* patch_t = fbase;
    float* patch_s = patch_t + PATCH_MAX;
    float* cp_t    = patch_s + PATCH_MAX;
    float* cp_s    = cp_t + CP_MAX;
    float* sa_t    = cp_s + CP_MAX;
    float* sa_s    = sa_t + SA_MAX;
    float* tq_t    = sa_s + SA_MAX;
    float* tq_s    = tq_t + TQ_MAX;

    init_kernel<<<1, 32, 0, stream>>>(scal);

    for (int l = 0; l < 4; ++l) {
        const LayerCfg& L = g_layers[l];
        int H = L.H, W = L.H, C = L.C, psz = L.psz;
        int PP = psz * psz, HW = H * W;

        int pool_blk = ((PP + 63) / 64) * 64;
        pool_kernel<<<dim3(2 * NB * C), pool_blk, 0, stream>>>(
            ref_t[l], ref_s[l], bb, patch_t, patch_s, C, H, W, psz, L.ds);

        int ntq = NB * PP;
        tq_kernel<<<dim3((2 * ntq + 255) / 256), 256, 0, stream>>>(
            patch_t, patch_s, tq_t, tq_s, C, PP);

        dim3 cgrid(2 * NBLK);
        launch_corr(psz, cgrid, stream, test_t[l], test_s[l], patch_t, patch_s,
                    cp_t, cp_s, spart, C, H, W, L.cc, L.tilesX, L.nCh, NBLK);
        reduce_S_kernel<<<1, 256, 0, stream>>>(spart, scal + 2 * l, NBLK);

        int nsa = NB * HW;
        sumabs_kernel<<<dim3((2 * nsa + 255) / 256), 256, 0, stream>>>(
            test_t[l], test_s[l], sa_t, sa_s, C, HW);

        loss1_kernel<<<dim3(16), 256, 0, stream>>>(tq_s, tq_t, ntq, 1.0 / (double)ntq, scal + 8);
        loss2_kernel<<<dim3(256), 256, 0, stream>>>(cp_t, cp_s, sa_t, sa_s, scal + 2 * l,
                                                    L.nCh, HW, scal + 8);
    }

    fin_kernel<<<1, 1, 0, stream>>>(scal, out);
}